// Round 2
// baseline (1396.247 us; speedup 1.0000x reference)
//
#include <hip/hip_runtime.h>
#include <hip/hip_bf16.h>
#include <cstdint>

#define H 1024
#define F 2048
#define E 8
#define T_TOK 4096
#define NPAIR (T_TOK * 2)   // top-2 per token
#define BK 32               // K-step per LDS tile
#define TM2 32              // m-tiles of 128 per expert (4096/128)

typedef __attribute__((ext_vector_type(8))) short short8;
typedef __attribute__((ext_vector_type(4))) float f32x4;

__device__ __forceinline__ ushort f2bf(float f) {
  uint32_t u = __builtin_bit_cast(uint32_t, f);
  u += 0x7FFF + ((u >> 16) & 1);   // RNE
  return (ushort)(u >> 16);
}

// async global->LDS, 16B per lane; LDS dest = wave-uniform base + lane*16
__device__ __forceinline__ void async_copy16(const ushort* g, ushort* l) {
  __builtin_amdgcn_global_load_lds(
      (const __attribute__((address_space(1))) unsigned int*)g,
      (__attribute__((address_space(3))) unsigned int*)l, 16, 0, 0);
}

// ---------------- router: fp32 logits, softmax, top-2, counts ----------------
__global__ __launch_bounds__(256) void router_kernel(
    const float* __restrict__ x, const float* __restrict__ gw,
    float* __restrict__ logits_out, int* __restrict__ sel,
    float* __restrict__ selw, int* __restrict__ counts) {
  int tid = threadIdx.x;
  int t = blockIdx.x * 4 + (tid >> 6);   // one wave per token
  int l = tid & 63;
  const float4* xr = (const float4*)(x + (size_t)t * H);
  const float4* g4 = (const float4*)gw;
  float acc[E];
#pragma unroll
  for (int e = 0; e < E; ++e) acc[e] = 0.f;
#pragma unroll
  for (int i = 0; i < 4; ++i) {
    float4 xv = xr[l + 64 * i];
#pragma unroll
    for (int e = 0; e < E; ++e) {
      float4 gv = g4[e * (H / 4) + l + 64 * i];
      acc[e] += xv.x * gv.x + xv.y * gv.y + xv.z * gv.z + xv.w * gv.w;
    }
  }
#pragma unroll
  for (int off = 32; off > 0; off >>= 1)
#pragma unroll
    for (int e = 0; e < E; ++e) acc[e] += __shfl_xor(acc[e], off, 64);

  if (l == 0) {
    float m = acc[0];
    for (int e = 1; e < E; ++e) m = fmaxf(m, acc[e]);
    float p[E], den = 0.f;
    for (int e = 0; e < E; ++e) { p[e] = __expf(acc[e] - m); den += p[e]; }
    float inv = 1.f / den;
    int i0 = 0;
    for (int e = 1; e < E; ++e) if (acc[e] > acc[i0]) i0 = e;
    int i1 = (i0 == 0) ? 1 : 0;
    for (int e = 0; e < E; ++e) if (e != i0 && acc[e] > acc[i1]) i1 = e;
    for (int e = 0; e < E; ++e) logits_out[t * E + e] = acc[e];
    sel[t * 2] = i0; sel[t * 2 + 1] = i1;
    selw[t * 2] = p[i0] * inv; selw[t * 2 + 1] = p[i1] * inv;
    atomicAdd(&counts[i0], 1);
    atomicAdd(&counts[i1], 1);
  }
}

__global__ void offsets_kernel(const int* __restrict__ counts, int* __restrict__ offsets) {
  if (threadIdx.x == 0 && blockIdx.x == 0) {
    int s = 0;
    for (int e = 0; e < E; ++e) { offsets[e] = s; s += counts[e]; }
  }
}

__global__ __launch_bounds__(256) void bucket_kernel(
    const int* __restrict__ sel, const float* __restrict__ selw,
    const int* __restrict__ offsets, int* __restrict__ poscnt,
    int* __restrict__ pair_token, float* __restrict__ pair_weight,
    int* __restrict__ pair_slot) {
  int t = blockIdx.x * 256 + threadIdx.x;
  if (t >= T_TOK) return;
  for (int k = 0; k < 2; ++k) {
    int e = sel[t * 2 + k];
    int pos = atomicAdd(&poscnt[e], 1);
    int slot = offsets[e] + pos;
    pair_token[slot] = t;
    pair_weight[slot] = selw[t * 2 + k];
    pair_slot[t * 2 + k] = slot;
  }
}

// ---------------- dtype conversion ----------------
__global__ __launch_bounds__(256) void cast_x_kernel(const float* __restrict__ x,
                                                     ushort* __restrict__ xb) {
  int i = (blockIdx.x * 256 + threadIdx.x) * 4;
  float4 v = *(const float4*)(x + i);
  ushort4 o = make_ushort4(f2bf(v.x), f2bf(v.y), f2bf(v.z), f2bf(v.w));
  *(ushort4*)(xb + i) = o;
}

// src fp32 [e][R][C] -> dst bf16 [e][C][R]  (N-major so GEMM frags are K-contiguous)
__global__ __launch_bounds__(256) void transpose_cast_kernel(
    const float* __restrict__ src, ushort* __restrict__ dst, int R, int C) {
  __shared__ ushort tile[64][65];
  int e = blockIdx.z;
  src += (size_t)e * R * C;
  dst += (size_t)e * R * C;
  int r0 = blockIdx.y * 64, c0 = blockIdx.x * 64;
  int tid = threadIdx.x;
  int tr = tid >> 4, tc = (tid & 15) * 4;
#pragma unroll
  for (int i = 0; i < 4; ++i) {
    float4 v = *(const float4*)(src + (size_t)(r0 + tr + 16 * i) * C + c0 + tc);
    tile[tr + 16 * i][tc + 0] = f2bf(v.x);
    tile[tr + 16 * i][tc + 1] = f2bf(v.y);
    tile[tr + 16 * i][tc + 2] = f2bf(v.z);
    tile[tr + 16 * i][tc + 3] = f2bf(v.w);
  }
  __syncthreads();
#pragma unroll
  for (int i = 0; i < 4; ++i) {
    int dr = tr + 16 * i;           // dest row = source col
    ushort4 o;
    o.x = tile[tc + 0][dr]; o.y = tile[tc + 1][dr];
    o.z = tile[tc + 2][dr]; o.w = tile[tc + 3][dr];
    *(ushort4*)(dst + (size_t)(c0 + dr) * R + r0 + tc) = o;
  }
}

// ---------------- grouped GEMM A: h = silu(x@w1) * (x@w3) ----------------
// 128x128 tile, BK=32, chunk-major LDS: addr(chunk,row) = (chunk*128+row)*16B
__global__ __launch_bounds__(256) void gemm_h_kernel(
    const ushort* __restrict__ xb, const ushort* __restrict__ w1t,
    const ushort* __restrict__ w3t, const int* __restrict__ pair_token,
    const int* __restrict__ counts, const int* __restrict__ offsets,
    ushort* __restrict__ hbuf) {
  int e = blockIdx.x >> 5;
  int mt = blockIdx.x & 31;
  int cnt = counts[e];
  int m0 = mt * 128;
  if (m0 >= cnt) return;
  int base = offsets[e];
  int f0 = blockIdx.y * 128;

  __shared__ ushort As[4096], B1s[4096], B3s[4096];   // 8 KB each

  int tid = threadIdx.x;
  int w = tid >> 6, l = tid & 63;

  // staging: wave w owns chunk w (k-elems w*8..w*8+7), rows l and l+64
  int p0 = base + m0 + l;        if (p0 >= base + cnt) p0 = base + cnt - 1;
  int p1 = base + m0 + l + 64;   if (p1 >= base + cnt) p1 = base + cnt - 1;
  const ushort* gA0 = xb + (size_t)pair_token[p0] * H + w * 8;
  const ushort* gA1 = xb + (size_t)pair_token[p1] * H + w * 8;
  const ushort* gB10 = w1t + ((size_t)e * F + f0 + l) * H + w * 8;
  const ushort* gB11 = gB10 + (size_t)64 * H;
  const ushort* gB30 = w3t + ((size_t)e * F + f0 + l) * H + w * 8;
  const ushort* gB31 = gB30 + (size_t)64 * H;
  ushort* ldsA0 = As + w * 1024;        // bytes: w*2048
  ushort* ldsA1 = As + w * 1024 + 512;
  ushort* ldsB10 = B1s + w * 1024;
  ushort* ldsB11 = B1s + w * 1024 + 512;
  ushort* ldsB30 = B3s + w * 1024;
  ushort* ldsB31 = B3s + w * 1024 + 512;

  int wm = w >> 1, wn = w & 1;
  int lr = l & 15, lkb = l >> 4;       // frag: row lr within 16, chunk lkb

  f32x4 c1[4][4], c3[4][4];
#pragma unroll
  for (int a = 0; a < 4; ++a)
#pragma unroll
    for (int b = 0; b < 4; ++b) { c1[a][b] = (f32x4)0.f; c3[a][b] = (f32x4)0.f; }

  for (int k0 = 0; k0 < H; k0 += BK) {
    __syncthreads();                    // prev-iter frag reads done
    async_copy16(gA0, ldsA0);  async_copy16(gA1, ldsA1);
    async_copy16(gB10, ldsB10); async_copy16(gB11, ldsB11);
    async_copy16(gB30, ldsB30); async_copy16(gB31, ldsB31);
    gA0 += BK; gA1 += BK; gB10 += BK; gB11 += BK; gB30 += BK; gB31 += BK;
    __syncthreads();                    // drains vmcnt -> LDS valid

    short8 af[4], b1f[4], b3f[4];
#pragma unroll
    for (int ms = 0; ms < 4; ++ms)
      af[ms] = *(const short8*)(As + (lkb * 128 + wm * 64 + ms * 16 + lr) * 8);
#pragma unroll
    for (int ns = 0; ns < 4; ++ns) {
      b1f[ns] = *(const short8*)(B1s + (lkb * 128 + wn * 64 + ns * 16 + lr) * 8);
      b3f[ns] = *(const short8*)(B3s + (lkb * 128 + wn * 64 + ns * 16 + lr) * 8);
    }
#pragma unroll
    for (int ms = 0; ms < 4; ++ms)
#pragma unroll
      for (int ns = 0; ns < 4; ++ns) {
        c1[ms][ns] = __builtin_amdgcn_mfma_f32_16x16x32_bf16(af[ms], b1f[ns], c1[ms][ns], 0, 0, 0);
        c3[ms][ns] = __builtin_amdgcn_mfma_f32_16x16x32_bf16(af[ms], b3f[ns], c3[ms][ns], 0, 0, 0);
      }
  }

#pragma unroll
  for (int ms = 0; ms < 4; ++ms)
#pragma unroll
    for (int ns = 0; ns < 4; ++ns)
#pragma unroll
      for (int rg = 0; rg < 4; ++rg) {
        int ml = wm * 64 + ms * 16 + (l >> 4) * 4 + rg;   // C/D: row=(lane>>4)*4+reg
        if (m0 + ml < cnt) {
          int nl = wn * 64 + ns * 16 + (l & 15);          // col=lane&15
          float g = c1[ms][ns][rg], u = c3[ms][ns][rg];
          float hv = g / (1.f + __expf(-g)) * u;          // silu(g)*u
          hbuf[(size_t)(base + m0 + ml) * F + f0 + nl] = f2bf(hv);
        }
      }
}

// ---------------- grouped GEMM B: po = weight * (h @ w2), per-pair rows -------
__global__ __launch_bounds__(256) void gemm_out_kernel(
    const ushort* __restrict__ hbuf, const ushort* __restrict__ w2t,
    const float* __restrict__ pair_weight, const int* __restrict__ counts,
    const int* __restrict__ offsets, float* __restrict__ po) {
  int e = blockIdx.x >> 5;
  int mt = blockIdx.x & 31;
  int cnt = counts[e];
  int m0 = mt * 128;
  if (m0 >= cnt) return;
  int base = offsets[e];
  int n0 = blockIdx.y * 128;

  __shared__ ushort As[4096], Bs[4096];
  __shared__ float wt_s[128];

  int tid = threadIdx.x;
  int w = tid >> 6, l = tid & 63;

  if (tid < 128) {
    int p = base + m0 + tid;
    if (p >= base + cnt) p = base + cnt - 1;
    wt_s[tid] = pair_weight[p];
  }

  int p0 = base + m0 + l;       if (p0 >= base + cnt) p0 = base + cnt - 1;
  int p1 = base + m0 + l + 64;  if (p1 >= base + cnt) p1 = base + cnt - 1;
  const ushort* gA0 = hbuf + (size_t)p0 * F + w * 8;
  const ushort* gA1 = hbuf + (size_t)p1 * F + w * 8;
  const ushort* gB0 = w2t + ((size_t)e * H + n0 + l) * F + w * 8;
  const ushort* gB1 = gB0 + (size_t)64 * F;
  ushort* ldsA0 = As + w * 1024;
  ushort* ldsA1 = As + w * 1024 + 512;
  ushort* ldsB0 = Bs + w * 1024;
  ushort* ldsB1 = Bs + w * 1024 + 512;

  int wm = w >> 1, wn = w & 1;
  int lr = l & 15, lkb = l >> 4;

  f32x4 cc[4][4];
#pragma unroll
  for (int a = 0; a < 4; ++a)
#pragma unroll
    for (int b = 0; b < 4; ++b) cc[a][b] = (f32x4)0.f;

  for (int k0 = 0; k0 < F; k0 += BK) {
    __syncthreads();
    async_copy16(gA0, ldsA0); async_copy16(gA1, ldsA1);
    async_copy16(gB0, ldsB0); async_copy16(gB1, ldsB1);
    gA0 += BK; gA1 += BK; gB0 += BK; gB1 += BK;
    __syncthreads();

    short8 af[4], bf_[4];
#pragma unroll
    for (int ms = 0; ms < 4; ++ms)
      af[ms] = *(const short8*)(As + (lkb * 128 + wm * 64 + ms * 16 + lr) * 8);
#pragma unroll
    for (int ns = 0; ns < 4; ++ns)
      bf_[ns] = *(const short8*)(Bs + (lkb * 128 + wn * 64 + ns * 16 + lr) * 8);
#pragma unroll
    for (int ms = 0; ms < 4; ++ms)
#pragma unroll
      for (int ns = 0; ns < 4; ++ns)
        cc[ms][ns] = __builtin_amdgcn_mfma_f32_16x16x32_bf16(af[ms], bf_[ns], cc[ms][ns], 0, 0, 0);
  }

#pragma unroll
  for (int ms = 0; ms < 4; ++ms)
#pragma unroll
    for (int ns = 0; ns < 4; ++ns)
#pragma unroll
      for (int rg = 0; rg < 4; ++rg) {
        int ml = wm * 64 + ms * 16 + (l >> 4) * 4 + rg;
        if (m0 + ml < cnt) {
          int nl = wn * 64 + ns * 16 + (l & 15);
          po[(size_t)(base + m0 + ml) * H + n0 + nl] = cc[ms][ns][rg] * wt_s[ml];
        }
      }
}

// ---------------- combine: y[t] = po[slot0] + po[slot1] ----------------
__global__ __launch_bounds__(256) void combine_kernel(
    const float* __restrict__ po, const int* __restrict__ pair_slot,
    float* __restrict__ y) {
  int idx = blockIdx.x * 256 + threadIdx.x;    // over T*H/4
  int t = idx >> 8;                            // H/4 = 256 float4 per token
  int c = (idx & 255) * 4;
  int s0 = pair_slot[t * 2], s1 = pair_slot[t * 2 + 1];
  float4 a = *(const float4*)(po + (size_t)s0 * H + c);
  float4 b = *(const float4*)(po + (size_t)s1 * H + c);
  float4 o = make_float4(a.x + b.x, a.y + b.y, a.z + b.z, a.w + b.w);
  *(float4*)(y + (size_t)t * H + c) = o;
}

extern "C" void kernel_launch(void* const* d_in, const int* in_sizes, int n_in,
                              void* d_out, int out_size, void* d_ws, size_t ws_size,
                              hipStream_t stream) {
  const float* x  = (const float*)d_in[0];
  const float* gw = (const float*)d_in[1];
  const float* w1 = (const float*)d_in[2];
  const float* w3 = (const float*)d_in[3];
  const float* w2 = (const float*)d_in[4];
  float* y = (float*)d_out;                       // [T, H] fp32
  float* logits_out = y + (size_t)T_TOK * H;      // [T, E] fp32 (output #2)

  char* ws = (char*)d_ws;
  size_t off = 0;
  auto alloc = [&](size_t bytes) {
    char* p = ws + off;
    off += (bytes + 255) & ~size_t(255);
    return p;
  };
  ushort* xb   = (ushort*)alloc((size_t)T_TOK * H * 2);
  ushort* w1t  = (ushort*)alloc((size_t)E * F * H * 2);
  ushort* w3t  = (ushort*)alloc((size_t)E * F * H * 2);
  ushort* w2t  = (ushort*)alloc((size_t)E * H * F * 2);
  ushort* hbuf = (ushort*)alloc((size_t)(NPAIR + 128) * F * 2);
  int*   pair_token  = (int*)alloc(NPAIR * 4);
  float* pair_weight = (float*)alloc(NPAIR * 4);
  int*   pair_slot   = (int*)alloc(NPAIR * 4);
  int*   sel   = (int*)alloc(T_TOK * 2 * 4);
  float* selw  = (float*)alloc(T_TOK * 2 * 4);
  int* counts  = (int*)alloc(E * 4);
  int* offsets = (int*)alloc(E * 4);
  int* poscnt  = (int*)alloc(E * 4);
  // po aliases w1t: w1t (E*F*H*2 = 32 MB) is dead after gemm_h; po needs
  // NPAIR*H*4 = 32 MB. Stream-ordered: gemm_out runs after gemm_h.
  float* po = (float*)w1t;

  hipMemsetAsync(counts, 0, E * 4, stream);
  hipMemsetAsync(poscnt, 0, E * 4, stream);

  router_kernel<<<T_TOK / 4, 256, 0, stream>>>(x, gw, logits_out, sel, selw, counts);
  offsets_kernel<<<1, 64, 0, stream>>>(counts, offsets);
  bucket_kernel<<<T_TOK / 256, 256, 0, stream>>>(sel, selw, offsets, poscnt,
                                                 pair_token, pair_weight, pair_slot);
  cast_x_kernel<<<(T_TOK * H / 4) / 256, 256, 0, stream>>>(x, xb);
  transpose_cast_kernel<<<dim3(F / 64, H / 64, E), 256, 0, stream>>>(w1, w1t, H, F);
  transpose_cast_kernel<<<dim3(F / 64, H / 64, E), 256, 0, stream>>>(w3, w3t, H, F);
  transpose_cast_kernel<<<dim3(H / 64, F / 64, E), 256, 0, stream>>>(w2, w2t, F, H);
  gemm_h_kernel<<<dim3(E * TM2, F / 128), 256, 0, stream>>>(xb, w1t, w3t, pair_token,
                                                            counts, offsets, hbuf);
  gemm_out_kernel<<<dim3(E * TM2, H / 128), 256, 0, stream>>>(hbuf, w2t, pair_weight,
                                                              counts, offsets, po);
  combine_kernel<<<(T_TOK * H / 4) / 256, 256, 0, stream>>>(po, pair_slot, y);
}

// Round 3
// 1064.218 us; speedup vs baseline: 1.3120x; 1.3120x over previous
//
#include <hip/hip_runtime.h>
#include <hip/hip_bf16.h>
#include <cstdint>

#define H 1024
#define F 2048
#define E 8
#define T_TOK 4096
#define NPAIR (T_TOK * 2)   // top-2 per token
#define BK 32               // K-step per LDS tile
#define TM2 32              // m-tiles of 128 per expert (4096/128)

typedef __attribute__((ext_vector_type(8))) short short8;
typedef __attribute__((ext_vector_type(4))) float f32x4;

__device__ __forceinline__ ushort f2bf(float f) {
  uint32_t u = __builtin_bit_cast(uint32_t, f);
  u += 0x7FFF + ((u >> 16) & 1);   // RNE
  return (ushort)(u >> 16);
}

// async global->LDS, 16B per lane; LDS dest = wave-uniform base + lane*16
__device__ __forceinline__ void async_copy16(const ushort* g, ushort* l) {
  __builtin_amdgcn_global_load_lds(
      (const __attribute__((address_space(1))) unsigned int*)g,
      (__attribute__((address_space(3))) unsigned int*)l, 16, 0, 0);
}

// ---------------- router: fp32 logits, softmax, top-2, counts ----------------
__global__ __launch_bounds__(256) void router_kernel(
    const float* __restrict__ x, const float* __restrict__ gw,
    float* __restrict__ logits_out, int* __restrict__ sel,
    float* __restrict__ selw, int* __restrict__ counts) {
  int tid = threadIdx.x;
  int t = blockIdx.x * 4 + (tid >> 6);   // one wave per token
  int l = tid & 63;
  const float4* xr = (const float4*)(x + (size_t)t * H);
  const float4* g4 = (const float4*)gw;
  float acc[E];
#pragma unroll
  for (int e = 0; e < E; ++e) acc[e] = 0.f;
#pragma unroll
  for (int i = 0; i < 4; ++i) {
    float4 xv = xr[l + 64 * i];
#pragma unroll
    for (int e = 0; e < E; ++e) {
      float4 gv = g4[e * (H / 4) + l + 64 * i];
      acc[e] += xv.x * gv.x + xv.y * gv.y + xv.z * gv.z + xv.w * gv.w;
    }
  }
#pragma unroll
  for (int off = 32; off > 0; off >>= 1)
#pragma unroll
    for (int e = 0; e < E; ++e) acc[e] += __shfl_xor(acc[e], off, 64);

  if (l == 0) {
    float m = acc[0];
    for (int e = 1; e < E; ++e) m = fmaxf(m, acc[e]);
    float p[E], den = 0.f;
    for (int e = 0; e < E; ++e) { p[e] = __expf(acc[e] - m); den += p[e]; }
    float inv = 1.f / den;
    int i0 = 0;
    for (int e = 1; e < E; ++e) if (acc[e] > acc[i0]) i0 = e;
    int i1 = (i0 == 0) ? 1 : 0;
    for (int e = 0; e < E; ++e) if (e != i0 && acc[e] > acc[i1]) i1 = e;
    for (int e = 0; e < E; ++e) logits_out[t * E + e] = acc[e];
    sel[t * 2] = i0; sel[t * 2 + 1] = i1;
    selw[t * 2] = p[i0] * inv; selw[t * 2 + 1] = p[i1] * inv;
    atomicAdd(&counts[i0], 1);
    atomicAdd(&counts[i1], 1);
  }
}

__global__ void offsets_kernel(const int* __restrict__ counts, int* __restrict__ offsets) {
  if (threadIdx.x == 0 && blockIdx.x == 0) {
    int s = 0;
    for (int e = 0; e < E; ++e) { offsets[e] = s; s += counts[e]; }
  }
}

__global__ __launch_bounds__(256) void bucket_kernel(
    const int* __restrict__ sel, const float* __restrict__ selw,
    const int* __restrict__ offsets, int* __restrict__ poscnt,
    int* __restrict__ pair_token, float* __restrict__ pair_weight,
    int* __restrict__ pair_slot) {
  int t = blockIdx.x * 256 + threadIdx.x;
  if (t >= T_TOK) return;
  for (int k = 0; k < 2; ++k) {
    int e = sel[t * 2 + k];
    int pos = atomicAdd(&poscnt[e], 1);
    int slot = offsets[e] + pos;
    pair_token[slot] = t;
    pair_weight[slot] = selw[t * 2 + k];
    pair_slot[t * 2 + k] = slot;
  }
}

// ---------------- dtype conversion ----------------
__global__ __launch_bounds__(256) void cast_x_kernel(const float* __restrict__ x,
                                                     ushort* __restrict__ xb) {
  int i = (blockIdx.x * 256 + threadIdx.x) * 4;
  float4 v = *(const float4*)(x + i);
  ushort4 o = make_ushort4(f2bf(v.x), f2bf(v.y), f2bf(v.z), f2bf(v.w));
  *(ushort4*)(xb + i) = o;
}

// src fp32 [e][R][C] -> dst bf16 [e][C][R]  (N-major so GEMM frags are K-contiguous)
__global__ __launch_bounds__(256) void transpose_cast_kernel(
    const float* __restrict__ src, ushort* __restrict__ dst, int R, int C) {
  __shared__ ushort tile[64][65];
  int e = blockIdx.z;
  src += (size_t)e * R * C;
  dst += (size_t)e * R * C;
  int r0 = blockIdx.y * 64, c0 = blockIdx.x * 64;
  int tid = threadIdx.x;
  int tr = tid >> 4, tc = (tid & 15) * 4;
#pragma unroll
  for (int i = 0; i < 4; ++i) {
    float4 v = *(const float4*)(src + (size_t)(r0 + tr + 16 * i) * C + c0 + tc);
    tile[tr + 16 * i][tc + 0] = f2bf(v.x);
    tile[tr + 16 * i][tc + 1] = f2bf(v.y);
    tile[tr + 16 * i][tc + 2] = f2bf(v.z);
    tile[tr + 16 * i][tc + 3] = f2bf(v.w);
  }
  __syncthreads();
#pragma unroll
  for (int i = 0; i < 4; ++i) {
    int dr = tr + 16 * i;           // dest row = source col
    ushort4 o;
    o.x = tile[tc + 0][dr]; o.y = tile[tc + 1][dr];
    o.z = tile[tc + 2][dr]; o.w = tile[tc + 3][dr];
    *(ushort4*)(dst + (size_t)(c0 + dr) * R + r0 + tc) = o;
  }
}

// ===================== GEMM tiles =====================
// LDS tile: 128 rows x BK(=32) k-elems, row-major, 64B/row (32 ushorts).
// Chunk swizzle: 16B slot s of row r holds k-chunk (s ^ ((r>>1)&3)).
//  - staging: lanes 4q..4q+3 cover row (R0+q)'s full 64B K-segment (coalesced,
//    chunks permuted within the segment); LDS dest = base + lane*16 (HW rule).
//  - frag reads: chunk c of row r at slot c^((r>>1)&3) -> 16B groups spread
//    evenly over banks (2 lanes/bank for b128 = free, m136).

__device__ __forceinline__ int frag_off(int rr, int lkb) {   // ushort offset
  return rr * 32 + ((lkb ^ ((rr >> 1) & 3)) * 8);
}

// ---------------- grouped GEMM A: h = silu(x@w1) * (x@w3) ----------------
__global__ __launch_bounds__(256) void gemm_h_kernel(
    const ushort* __restrict__ xb, const ushort* __restrict__ w1t,
    const ushort* __restrict__ w3t, const int* __restrict__ pair_token,
    const int* __restrict__ counts, const int* __restrict__ offsets,
    ushort* __restrict__ hbuf) {
  int e = blockIdx.x >> 5;
  int mt = blockIdx.x & 31;
  int cnt = counts[e];
  int m0 = mt * 128;
  if (m0 >= cnt) return;
  int base = offsets[e];
  int f0 = blockIdx.y * 128;

  __shared__ ushort As[4096], B1s[4096], B3s[4096];   // 8 KB each

  int tid = threadIdx.x;
  int w = tid >> 6, l = tid & 63;
  int q = l >> 2, s = l & 3;

  // rows handled by this wave's two staging instrs: w*32+q and w*32+16+q
  int row0 = w * 32 + q, row1 = row0 + 16;
  int g0 = s ^ ((row0 >> 1) & 3);       // swizzled global k-chunk
  int g1 = s ^ ((row1 >> 1) & 3);

  int pA0 = base + m0 + row0; if (pA0 >= base + cnt) pA0 = base + cnt - 1;
  int pA1 = base + m0 + row1; if (pA1 >= base + cnt) pA1 = base + cnt - 1;
  const ushort* gA0 = xb + (size_t)pair_token[pA0] * H + g0 * 8;
  const ushort* gA1 = xb + (size_t)pair_token[pA1] * H + g1 * 8;
  const ushort* gB10 = w1t + ((size_t)e * F + f0 + row0) * H + g0 * 8;
  const ushort* gB11 = w1t + ((size_t)e * F + f0 + row1) * H + g1 * 8;
  const ushort* gB30 = w3t + ((size_t)e * F + f0 + row0) * H + g0 * 8;
  const ushort* gB31 = w3t + ((size_t)e * F + f0 + row1) * H + g1 * 8;
  ushort* ldsA0 = As + w * 1024;        // row (w*32) * 32 ushorts
  ushort* ldsA1 = As + w * 1024 + 512;  // row (w*32+16)
  ushort* ldsB10 = B1s + w * 1024;
  ushort* ldsB11 = B1s + w * 1024 + 512;
  ushort* ldsB30 = B3s + w * 1024;
  ushort* ldsB31 = B3s + w * 1024 + 512;

  int wm = w >> 1, wn = w & 1;
  int lr = l & 15, lkb = l >> 4;

  int offA[4], offB[4];
#pragma unroll
  for (int ms = 0; ms < 4; ++ms) offA[ms] = frag_off(wm * 64 + ms * 16 + lr, lkb);
#pragma unroll
  for (int ns = 0; ns < 4; ++ns) offB[ns] = frag_off(wn * 64 + ns * 16 + lr, lkb);

  f32x4 c1[4][4], c3[4][4];
#pragma unroll
  for (int a = 0; a < 4; ++a)
#pragma unroll
    for (int b = 0; b < 4; ++b) { c1[a][b] = (f32x4)0.f; c3[a][b] = (f32x4)0.f; }

  for (int k0 = 0; k0 < H; k0 += BK) {
    __syncthreads();                    // prev-iter frag reads done
    async_copy16(gA0, ldsA0);  async_copy16(gA1, ldsA1);
    async_copy16(gB10, ldsB10); async_copy16(gB11, ldsB11);
    async_copy16(gB30, ldsB30); async_copy16(gB31, ldsB31);
    gA0 += BK; gA1 += BK; gB10 += BK; gB11 += BK; gB30 += BK; gB31 += BK;
    __syncthreads();                    // drains vmcnt -> LDS valid

    short8 af[4], b1f[4], b3f[4];
#pragma unroll
    for (int ms = 0; ms < 4; ++ms) af[ms] = *(const short8*)(As + offA[ms]);
#pragma unroll
    for (int ns = 0; ns < 4; ++ns) {
      b1f[ns] = *(const short8*)(B1s + offB[ns]);
      b3f[ns] = *(const short8*)(B3s + offB[ns]);
    }
#pragma unroll
    for (int ms = 0; ms < 4; ++ms)
#pragma unroll
      for (int ns = 0; ns < 4; ++ns) {
        c1[ms][ns] = __builtin_amdgcn_mfma_f32_16x16x32_bf16(af[ms], b1f[ns], c1[ms][ns], 0, 0, 0);
        c3[ms][ns] = __builtin_amdgcn_mfma_f32_16x16x32_bf16(af[ms], b3f[ns], c3[ms][ns], 0, 0, 0);
      }
  }

#pragma unroll
  for (int ms = 0; ms < 4; ++ms)
#pragma unroll
    for (int ns = 0; ns < 4; ++ns)
#pragma unroll
      for (int rg = 0; rg < 4; ++rg) {
        int ml = wm * 64 + ms * 16 + (l >> 4) * 4 + rg;   // C/D: row=(lane>>4)*4+reg
        if (m0 + ml < cnt) {
          int nl = wn * 64 + ns * 16 + (l & 15);          // col=lane&15
          float g = c1[ms][ns][rg], u = c3[ms][ns][rg];
          float hv = g / (1.f + __expf(-g)) * u;          // silu(g)*u
          hbuf[(size_t)(base + m0 + ml) * F + f0 + nl] = f2bf(hv);
        }
      }
}

// ---------------- grouped GEMM B: po = weight * (h @ w2), per-pair rows -------
__global__ __launch_bounds__(256) void gemm_out_kernel(
    const ushort* __restrict__ hbuf, const ushort* __restrict__ w2t,
    const float* __restrict__ pair_weight, const int* __restrict__ counts,
    const int* __restrict__ offsets, float* __restrict__ po) {
  int e = blockIdx.x >> 5;
  int mt = blockIdx.x & 31;
  int cnt = counts[e];
  int m0 = mt * 128;
  if (m0 >= cnt) return;
  int base = offsets[e];
  int n0 = blockIdx.y * 128;

  __shared__ ushort As[4096], Bs[4096];
  __shared__ float wt_s[128];

  int tid = threadIdx.x;
  int w = tid >> 6, l = tid & 63;
  int q = l >> 2, s = l & 3;

  if (tid < 128) {
    int p = base + m0 + tid;
    if (p >= base + cnt) p = base + cnt - 1;
    wt_s[tid] = pair_weight[p];
  }

  int row0 = w * 32 + q, row1 = row0 + 16;
  int g0 = s ^ ((row0 >> 1) & 3);
  int g1 = s ^ ((row1 >> 1) & 3);

  int pA0 = base + m0 + row0; if (pA0 >= base + cnt) pA0 = base + cnt - 1;
  int pA1 = base + m0 + row1; if (pA1 >= base + cnt) pA1 = base + cnt - 1;
  const ushort* gA0 = hbuf + (size_t)pA0 * F + g0 * 8;
  const ushort* gA1 = hbuf + (size_t)pA1 * F + g1 * 8;
  const ushort* gB0 = w2t + ((size_t)e * H + n0 + row0) * F + g0 * 8;
  const ushort* gB1 = w2t + ((size_t)e * H + n0 + row1) * F + g1 * 8;
  ushort* ldsA0 = As + w * 1024;
  ushort* ldsA1 = As + w * 1024 + 512;
  ushort* ldsB0 = Bs + w * 1024;
  ushort* ldsB1 = Bs + w * 1024 + 512;

  int wm = w >> 1, wn = w & 1;
  int lr = l & 15, lkb = l >> 4;

  int offA[4], offB[4];
#pragma unroll
  for (int ms = 0; ms < 4; ++ms) offA[ms] = frag_off(wm * 64 + ms * 16 + lr, lkb);
#pragma unroll
  for (int ns = 0; ns < 4; ++ns) offB[ns] = frag_off(wn * 64 + ns * 16 + lr, lkb);

  f32x4 cc[4][4];
#pragma unroll
  for (int a = 0; a < 4; ++a)
#pragma unroll
    for (int b = 0; b < 4; ++b) cc[a][b] = (f32x4)0.f;

  for (int k0 = 0; k0 < F; k0 += BK) {
    __syncthreads();
    async_copy16(gA0, ldsA0); async_copy16(gA1, ldsA1);
    async_copy16(gB0, ldsB0); async_copy16(gB1, ldsB1);
    gA0 += BK; gA1 += BK; gB0 += BK; gB1 += BK;
    __syncthreads();

    short8 af[4], bf_[4];
#pragma unroll
    for (int ms = 0; ms < 4; ++ms) af[ms] = *(const short8*)(As + offA[ms]);
#pragma unroll
    for (int ns = 0; ns < 4; ++ns) bf_[ns] = *(const short8*)(Bs + offB[ns]);
#pragma unroll
    for (int ms = 0; ms < 4; ++ms)
#pragma unroll
      for (int ns = 0; ns < 4; ++ns)
        cc[ms][ns] = __builtin_amdgcn_mfma_f32_16x16x32_bf16(af[ms], bf_[ns], cc[ms][ns], 0, 0, 0);
  }

#pragma unroll
  for (int ms = 0; ms < 4; ++ms)
#pragma unroll
    for (int ns = 0; ns < 4; ++ns)
#pragma unroll
      for (int rg = 0; rg < 4; ++rg) {
        int ml = wm * 64 + ms * 16 + (l >> 4) * 4 + rg;
        if (m0 + ml < cnt) {
          int nl = wn * 64 + ns * 16 + (l & 15);
          po[(size_t)(base + m0 + ml) * H + n0 + nl] = cc[ms][ns][rg] * wt_s[ml];
        }
      }
}

// ---------------- combine: y[t] = po[slot0] + po[slot1] ----------------
__global__ __launch_bounds__(256) void combine_kernel(
    const float* __restrict__ po, const int* __restrict__ pair_slot,
    float* __restrict__ y) {
  int idx = blockIdx.x * 256 + threadIdx.x;    // over T*H/4
  int t = idx >> 8;                            // H/4 = 256 float4 per token
  int c = (idx & 255) * 4;
  int s0 = pair_slot[t * 2], s1 = pair_slot[t * 2 + 1];
  float4 a = *(const float4*)(po + (size_t)s0 * H + c);
  float4 b = *(const float4*)(po + (size_t)s1 * H + c);
  float4 o = make_float4(a.x + b.x, a.y + b.y, a.z + b.z, a.w + b.w);
  *(float4*)(y + (size_t)t * H + c) = o;
}

extern "C" void kernel_launch(void* const* d_in, const int* in_sizes, int n_in,
                              void* d_out, int out_size, void* d_ws, size_t ws_size,
                              hipStream_t stream) {
  const float* x  = (const float*)d_in[0];
  const float* gw = (const float*)d_in[1];
  const float* w1 = (const float*)d_in[2];
  const float* w3 = (const float*)d_in[3];
  const float* w2 = (const float*)d_in[4];
  float* y = (float*)d_out;                       // [T, H] fp32
  float* logits_out = y + (size_t)T_TOK * H;      // [T, E] fp32 (output #2)

  char* ws = (char*)d_ws;
  size_t off = 0;
  auto alloc = [&](size_t bytes) {
    char* p = ws + off;
    off += (bytes + 255) & ~size_t(255);
    return p;
  };
  ushort* xb   = (ushort*)alloc((size_t)T_TOK * H * 2);
  ushort* w1t  = (ushort*)alloc((size_t)E * F * H * 2);
  ushort* w3t  = (ushort*)alloc((size_t)E * F * H * 2);
  ushort* w2t  = (ushort*)alloc((size_t)E * H * F * 2);
  ushort* hbuf = (ushort*)alloc((size_t)(NPAIR + 128) * F * 2);
  int*   pair_token  = (int*)alloc(NPAIR * 4);
  float* pair_weight = (float*)alloc(NPAIR * 4);
  int*   pair_slot   = (int*)alloc(NPAIR * 4);
  int*   sel   = (int*)alloc(T_TOK * 2 * 4);
  float* selw  = (float*)alloc(T_TOK * 2 * 4);
  int* counts  = (int*)alloc(E * 4);
  int* offsets = (int*)alloc(E * 4);
  int* poscnt  = (int*)alloc(E * 4);
  // po aliases w1t: w1t (32 MB) is dead after gemm_h; po needs NPAIR*H*4 = 32 MB.
  float* po = (float*)w1t;

  hipMemsetAsync(counts, 0, E * 4, stream);
  hipMemsetAsync(poscnt, 0, E * 4, stream);

  router_kernel<<<T_TOK / 4, 256, 0, stream>>>(x, gw, logits_out, sel, selw, counts);
  offsets_kernel<<<1, 64, 0, stream>>>(counts, offsets);
  bucket_kernel<<<T_TOK / 256, 256, 0, stream>>>(sel, selw, offsets, poscnt,
                                                 pair_token, pair_weight, pair_slot);
  cast_x_kernel<<<(T_TOK * H / 4) / 256, 256, 0, stream>>>(x, xb);
  transpose_cast_kernel<<<dim3(F / 64, H / 64, E), 256, 0, stream>>>(w1, w1t, H, F);
  transpose_cast_kernel<<<dim3(F / 64, H / 64, E), 256, 0, stream>>>(w3, w3t, H, F);
  transpose_cast_kernel<<<dim3(H / 64, F / 64, E), 256, 0, stream>>>(w2, w2t, F, H);
  gemm_h_kernel<<<dim3(E * TM2, F / 128), 256, 0, stream>>>(xb, w1t, w3t, pair_token,
                                                            counts, offsets, hbuf);
  gemm_out_kernel<<<dim3(E * TM2, H / 128), 256, 0, stream>>>(hbuf, w2t, pair_weight,
                                                              counts, offsets, po);
  combine_kernel<<<(T_TOK * H / 4) / 256, 256, 0, stream>>>(po, pair_slot, y);
}

// Round 4
// 813.117 us; speedup vs baseline: 1.7172x; 1.3088x over previous
//
#include <hip/hip_runtime.h>
#include <hip/hip_bf16.h>
#include <cstdint>

#define H 1024
#define F 2048
#define E 8
#define T_TOK 4096
#define NPAIR (T_TOK * 2)   // top-2 per token
#define BK 32               // K-step per LDS tile
#define TM2 32              // m-tiles of 128 per expert (4096/128)

typedef __attribute__((ext_vector_type(8))) short short8;
typedef __attribute__((ext_vector_type(4))) float f32x4;

__device__ __forceinline__ ushort f2bf(float f) {
  uint32_t u = __builtin_bit_cast(uint32_t, f);
  u += 0x7FFF + ((u >> 16) & 1);   // RNE
  return (ushort)(u >> 16);
}

// async global->LDS, 16B per lane; LDS dest = wave-uniform base + lane*16
__device__ __forceinline__ void async_copy16(const ushort* g, ushort* l) {
  __builtin_amdgcn_global_load_lds(
      (const __attribute__((address_space(1))) unsigned int*)g,
      (__attribute__((address_space(3))) unsigned int*)l, 16, 0, 0);
}

// ---------------- router: fp32 logits, softmax, top-2, counts ----------------
__global__ __launch_bounds__(256) void router_kernel(
    const float* __restrict__ x, const float* __restrict__ gw,
    float* __restrict__ logits_out, int* __restrict__ sel,
    float* __restrict__ selw, int* __restrict__ counts) {
  int tid = threadIdx.x;
  int t = blockIdx.x * 4 + (tid >> 6);   // one wave per token
  int l = tid & 63;
  const float4* xr = (const float4*)(x + (size_t)t * H);
  const float4* g4 = (const float4*)gw;
  float acc[E];
#pragma unroll
  for (int e = 0; e < E; ++e) acc[e] = 0.f;
#pragma unroll
  for (int i = 0; i < 4; ++i) {
    float4 xv = xr[l + 64 * i];
#pragma unroll
    for (int e = 0; e < E; ++e) {
      float4 gv = g4[e * (H / 4) + l + 64 * i];
      acc[e] += xv.x * gv.x + xv.y * gv.y + xv.z * gv.z + xv.w * gv.w;
    }
  }
#pragma unroll
  for (int off = 32; off > 0; off >>= 1)
#pragma unroll
    for (int e = 0; e < E; ++e) acc[e] += __shfl_xor(acc[e], off, 64);

  if (l == 0) {
    float m = acc[0];
    for (int e = 1; e < E; ++e) m = fmaxf(m, acc[e]);
    float p[E], den = 0.f;
    for (int e = 0; e < E; ++e) { p[e] = __expf(acc[e] - m); den += p[e]; }
    float inv = 1.f / den;
    int i0 = 0;
    for (int e = 1; e < E; ++e) if (acc[e] > acc[i0]) i0 = e;
    int i1 = (i0 == 0) ? 1 : 0;
    for (int e = 0; e < E; ++e) if (e != i0 && acc[e] > acc[i1]) i1 = e;
    for (int e = 0; e < E; ++e) logits_out[t * E + e] = acc[e];
    sel[t * 2] = i0; sel[t * 2 + 1] = i1;
    selw[t * 2] = p[i0] * inv; selw[t * 2 + 1] = p[i1] * inv;
    atomicAdd(&counts[i0], 1);
    atomicAdd(&counts[i1], 1);
  }
}

__global__ void offsets_kernel(const int* __restrict__ counts, int* __restrict__ offsets) {
  if (threadIdx.x == 0 && blockIdx.x == 0) {
    int s = 0;
    for (int e = 0; e < E; ++e) { offsets[e] = s; s += counts[e]; }
  }
}

__global__ __launch_bounds__(256) void bucket_kernel(
    const int* __restrict__ sel, const float* __restrict__ selw,
    const int* __restrict__ offsets, int* __restrict__ poscnt,
    int* __restrict__ pair_token, float* __restrict__ pair_weight,
    int* __restrict__ pair_slot) {
  int t = blockIdx.x * 256 + threadIdx.x;
  if (t >= T_TOK) return;
  for (int k = 0; k < 2; ++k) {
    int e = sel[t * 2 + k];
    int pos = atomicAdd(&poscnt[e], 1);
    int slot = offsets[e] + pos;
    pair_token[slot] = t;
    pair_weight[slot] = selw[t * 2 + k];
    pair_slot[t * 2 + k] = slot;
  }
}

// ---------------- dtype conversion ----------------
__global__ __launch_bounds__(256) void cast_x_kernel(const float* __restrict__ x,
                                                     ushort* __restrict__ xb) {
  int i = (blockIdx.x * 256 + threadIdx.x) * 4;
  float4 v = *(const float4*)(x + i);
  ushort4 o = make_ushort4(f2bf(v.x), f2bf(v.y), f2bf(v.z), f2bf(v.w));
  *(ushort4*)(xb + i) = o;
}

// src fp32 [e][R][C] -> dst bf16 [e][C][R]  (N-major so GEMM frags are K-contiguous)
__global__ __launch_bounds__(256) void transpose_cast_kernel(
    const float* __restrict__ src, ushort* __restrict__ dst, int R, int C) {
  __shared__ ushort tile[64][65];
  int e = blockIdx.z;
  src += (size_t)e * R * C;
  dst += (size_t)e * R * C;
  int r0 = blockIdx.y * 64, c0 = blockIdx.x * 64;
  int tid = threadIdx.x;
  int tr = tid >> 4, tc = (tid & 15) * 4;
#pragma unroll
  for (int i = 0; i < 4; ++i) {
    float4 v = *(const float4*)(src + (size_t)(r0 + tr + 16 * i) * C + c0 + tc);
    tile[tr + 16 * i][tc + 0] = f2bf(v.x);
    tile[tr + 16 * i][tc + 1] = f2bf(v.y);
    tile[tr + 16 * i][tc + 2] = f2bf(v.z);
    tile[tr + 16 * i][tc + 3] = f2bf(v.w);
  }
  __syncthreads();
#pragma unroll
  for (int i = 0; i < 4; ++i) {
    int dr = tr + 16 * i;           // dest row = source col
    ushort4 o;
    o.x = tile[tc + 0][dr]; o.y = tile[tc + 1][dr];
    o.z = tile[tc + 2][dr]; o.w = tile[tc + 3][dr];
    *(ushort4*)(dst + (size_t)(c0 + dr) * R + r0 + tc) = o;
  }
}

// ===================== GEMM tiles =====================
// LDS tile: 128 rows x BK(=32) k-elems, row-major, 64B/row (32 ushorts).
// Chunk swizzle: 16B slot s of row r holds k-chunk (s ^ ((r>>1)&3)).
//  - staging: lanes 4q..4q+3 cover row (R0+q)'s full 64B K-segment (coalesced,
//    chunks permuted within the segment); LDS dest = base + lane*16 (HW rule).
//  - frag reads: chunk c of row r at slot c^((r>>1)&3) -> 16B groups spread
//    evenly over banks (2 lanes/bank for b128 = free, m136).

__device__ __forceinline__ int frag_off(int rr, int lkb) {   // ushort offset
  return rr * 32 + ((lkb ^ ((rr >> 1) & 3)) * 8);
}

// ---------------- grouped GEMM A: h = silu(x@w1) * (x@w3) ----------------
// 512 threads = 8 waves; wave tile 64x32 -> c1+c3 = 64 AGPR/wave (reg cliff:
// R3's 4-wave version held 128 AGPR + 164 VGPR = 292 > 256 -> 1 wave/SIMD).
__global__ __launch_bounds__(512) void gemm_h_kernel(
    const ushort* __restrict__ xb, const ushort* __restrict__ w1t,
    const ushort* __restrict__ w3t, const int* __restrict__ pair_token,
    const int* __restrict__ counts, const int* __restrict__ offsets,
    ushort* __restrict__ hbuf) {
  int e = blockIdx.x >> 5;
  int mt = blockIdx.x & 31;
  int cnt = counts[e];
  int m0 = mt * 128;
  if (m0 >= cnt) return;
  int base = offsets[e];
  int f0 = blockIdx.y * 128;

  __shared__ ushort As[4096], B1s[4096], B3s[4096];   // 8 KB each

  int tid = threadIdx.x;
  int w = tid >> 6, l = tid & 63;     // w in 0..7
  int q = l >> 2, s = l & 3;

  // staging: wave w stages rows [w*16, w*16+16) of each of A, B1, B3
  int row = w * 16 + q;
  int g = s ^ ((row >> 1) & 3);       // swizzled global k-chunk

  int pA = base + m0 + row; if (pA >= base + cnt) pA = base + cnt - 1;
  const ushort* gA  = xb + (size_t)pair_token[pA] * H + g * 8;
  const ushort* gB1 = w1t + ((size_t)e * F + f0 + row) * H + g * 8;
  const ushort* gB3 = w3t + ((size_t)e * F + f0 + row) * H + g * 8;
  ushort* ldsA  = As  + w * 512;      // row (w*16) * 32 ushorts
  ushort* ldsB1 = B1s + w * 512;
  ushort* ldsB3 = B3s + w * 512;

  int wm = w >> 2, wn = w & 3;        // wave tile: rows wm*64+, cols wn*32+
  int lr = l & 15, lkb = l >> 4;

  int offA[4], offB[2];
#pragma unroll
  for (int ms = 0; ms < 4; ++ms) offA[ms] = frag_off(wm * 64 + ms * 16 + lr, lkb);
#pragma unroll
  for (int ns = 0; ns < 2; ++ns) offB[ns] = frag_off(wn * 32 + ns * 16 + lr, lkb);

  f32x4 c1[4][2], c3[4][2];
#pragma unroll
  for (int a = 0; a < 4; ++a)
#pragma unroll
    for (int b = 0; b < 2; ++b) { c1[a][b] = (f32x4)0.f; c3[a][b] = (f32x4)0.f; }

  for (int k0 = 0; k0 < H; k0 += BK) {
    __syncthreads();                    // prev-iter frag reads done
    async_copy16(gA, ldsA);
    async_copy16(gB1, ldsB1);
    async_copy16(gB3, ldsB3);
    gA += BK; gB1 += BK; gB3 += BK;
    __syncthreads();                    // drains vmcnt -> LDS valid

    short8 af[4], b1f[2], b3f[2];
#pragma unroll
    for (int ms = 0; ms < 4; ++ms) af[ms] = *(const short8*)(As + offA[ms]);
#pragma unroll
    for (int ns = 0; ns < 2; ++ns) {
      b1f[ns] = *(const short8*)(B1s + offB[ns]);
      b3f[ns] = *(const short8*)(B3s + offB[ns]);
    }
#pragma unroll
    for (int ms = 0; ms < 4; ++ms)
#pragma unroll
      for (int ns = 0; ns < 2; ++ns) {
        c1[ms][ns] = __builtin_amdgcn_mfma_f32_16x16x32_bf16(af[ms], b1f[ns], c1[ms][ns], 0, 0, 0);
        c3[ms][ns] = __builtin_amdgcn_mfma_f32_16x16x32_bf16(af[ms], b3f[ns], c3[ms][ns], 0, 0, 0);
      }
  }

#pragma unroll
  for (int ms = 0; ms < 4; ++ms)
#pragma unroll
    for (int ns = 0; ns < 2; ++ns)
#pragma unroll
      for (int rg = 0; rg < 4; ++rg) {
        int ml = wm * 64 + ms * 16 + (l >> 4) * 4 + rg;   // C/D: row=(lane>>4)*4+reg
        if (m0 + ml < cnt) {
          int nl = wn * 32 + ns * 16 + (l & 15);          // col=lane&15
          float gg = c1[ms][ns][rg], u = c3[ms][ns][rg];
          float hv = gg / (1.f + __expf(-gg)) * u;        // silu(g)*u
          hbuf[(size_t)(base + m0 + ml) * F + f0 + nl] = f2bf(hv);
        }
      }
}

// ---------------- grouped GEMM B: po = weight * (h @ w2), per-pair rows -------
__global__ __launch_bounds__(256) void gemm_out_kernel(
    const ushort* __restrict__ hbuf, const ushort* __restrict__ w2t,
    const float* __restrict__ pair_weight, const int* __restrict__ counts,
    const int* __restrict__ offsets, float* __restrict__ po) {
  int e = blockIdx.x >> 5;
  int mt = blockIdx.x & 31;
  int cnt = counts[e];
  int m0 = mt * 128;
  if (m0 >= cnt) return;
  int base = offsets[e];
  int n0 = blockIdx.y * 128;

  __shared__ ushort As[4096], Bs[4096];
  __shared__ float wt_s[128];

  int tid = threadIdx.x;
  int w = tid >> 6, l = tid & 63;
  int q = l >> 2, s = l & 3;

  if (tid < 128) {
    int p = base + m0 + tid;
    if (p >= base + cnt) p = base + cnt - 1;
    wt_s[tid] = pair_weight[p];
  }

  int row0 = w * 32 + q, row1 = row0 + 16;
  int g0 = s ^ ((row0 >> 1) & 3);
  int g1 = s ^ ((row1 >> 1) & 3);

  int pA0 = base + m0 + row0; if (pA0 >= base + cnt) pA0 = base + cnt - 1;
  int pA1 = base + m0 + row1; if (pA1 >= base + cnt) pA1 = base + cnt - 1;
  const ushort* gA0 = hbuf + (size_t)pA0 * F + g0 * 8;
  const ushort* gA1 = hbuf + (size_t)pA1 * F + g1 * 8;
  const ushort* gB0 = w2t + ((size_t)e * H + n0 + row0) * F + g0 * 8;
  const ushort* gB1 = w2t + ((size_t)e * H + n0 + row1) * F + g1 * 8;
  ushort* ldsA0 = As + w * 1024;
  ushort* ldsA1 = As + w * 1024 + 512;
  ushort* ldsB0 = Bs + w * 1024;
  ushort* ldsB1 = Bs + w * 1024 + 512;

  int wm = w >> 1, wn = w & 1;
  int lr = l & 15, lkb = l >> 4;

  int offA[4], offB[4];
#pragma unroll
  for (int ms = 0; ms < 4; ++ms) offA[ms] = frag_off(wm * 64 + ms * 16 + lr, lkb);
#pragma unroll
  for (int ns = 0; ns < 4; ++ns) offB[ns] = frag_off(wn * 64 + ns * 16 + lr, lkb);

  f32x4 cc[4][4];
#pragma unroll
  for (int a = 0; a < 4; ++a)
#pragma unroll
    for (int b = 0; b < 4; ++b) cc[a][b] = (f32x4)0.f;

  for (int k0 = 0; k0 < F; k0 += BK) {
    __syncthreads();
    async_copy16(gA0, ldsA0); async_copy16(gA1, ldsA1);
    async_copy16(gB0, ldsB0); async_copy16(gB1, ldsB1);
    gA0 += BK; gA1 += BK; gB0 += BK; gB1 += BK;
    __syncthreads();

    short8 af[4], bf_[4];
#pragma unroll
    for (int ms = 0; ms < 4; ++ms) af[ms] = *(const short8*)(As + offA[ms]);
#pragma unroll
    for (int ns = 0; ns < 4; ++ns) bf_[ns] = *(const short8*)(Bs + offB[ns]);
#pragma unroll
    for (int ms = 0; ms < 4; ++ms)
#pragma unroll
      for (int ns = 0; ns < 4; ++ns)
        cc[ms][ns] = __builtin_amdgcn_mfma_f32_16x16x32_bf16(af[ms], bf_[ns], cc[ms][ns], 0, 0, 0);
  }

#pragma unroll
  for (int ms = 0; ms < 4; ++ms)
#pragma unroll
    for (int ns = 0; ns < 4; ++ns)
#pragma unroll
      for (int rg = 0; rg < 4; ++rg) {
        int ml = wm * 64 + ms * 16 + (l >> 4) * 4 + rg;
        if (m0 + ml < cnt) {
          int nl = wn * 64 + ns * 16 + (l & 15);
          po[(size_t)(base + m0 + ml) * H + n0 + nl] = cc[ms][ns][rg] * wt_s[ml];
        }
      }
}

// ---------------- combine: y[t] = po[slot0] + po[slot1] ----------------
__global__ __launch_bounds__(256) void combine_kernel(
    const float* __restrict__ po, const int* __restrict__ pair_slot,
    float* __restrict__ y) {
  int idx = blockIdx.x * 256 + threadIdx.x;    // over T*H/4
  int t = idx >> 8;                            // H/4 = 256 float4 per token
  int c = (idx & 255) * 4;
  int s0 = pair_slot[t * 2], s1 = pair_slot[t * 2 + 1];
  float4 a = *(const float4*)(po + (size_t)s0 * H + c);
  float4 b = *(const float4*)(po + (size_t)s1 * H + c);
  float4 o = make_float4(a.x + b.x, a.y + b.y, a.z + b.z, a.w + b.w);
  *(float4*)(y + (size_t)t * H + c) = o;
}

extern "C" void kernel_launch(void* const* d_in, const int* in_sizes, int n_in,
                              void* d_out, int out_size, void* d_ws, size_t ws_size,
                              hipStream_t stream) {
  const float* x  = (const float*)d_in[0];
  const float* gw = (const float*)d_in[1];
  const float* w1 = (const float*)d_in[2];
  const float* w3 = (const float*)d_in[3];
  const float* w2 = (const float*)d_in[4];
  float* y = (float*)d_out;                       // [T, H] fp32
  float* logits_out = y + (size_t)T_TOK * H;      // [T, E] fp32 (output #2)

  char* ws = (char*)d_ws;
  size_t off = 0;
  auto alloc = [&](size_t bytes) {
    char* p = ws + off;
    off += (bytes + 255) & ~size_t(255);
    return p;
  };
  ushort* xb   = (ushort*)alloc((size_t)T_TOK * H * 2);
  ushort* w1t  = (ushort*)alloc((size_t)E * F * H * 2);
  ushort* w3t  = (ushort*)alloc((size_t)E * F * H * 2);
  ushort* w2t  = (ushort*)alloc((size_t)E * H * F * 2);
  ushort* hbuf = (ushort*)alloc((size_t)(NPAIR + 128) * F * 2);
  int*   pair_token  = (int*)alloc(NPAIR * 4);
  float* pair_weight = (float*)alloc(NPAIR * 4);
  int*   pair_slot   = (int*)alloc(NPAIR * 4);
  int*   sel   = (int*)alloc(T_TOK * 2 * 4);
  float* selw  = (float*)alloc(T_TOK * 2 * 4);
  int* counts  = (int*)alloc(E * 4);
  int* offsets = (int*)alloc(E * 4);
  int* poscnt  = (int*)alloc(E * 4);
  // po aliases w1t: w1t (32 MB) is dead after gemm_h; po needs NPAIR*H*4 = 32 MB.
  float* po = (float*)w1t;

  hipMemsetAsync(counts, 0, E * 4, stream);
  hipMemsetAsync(poscnt, 0, E * 4, stream);

  router_kernel<<<T_TOK / 4, 256, 0, stream>>>(x, gw, logits_out, sel, selw, counts);
  offsets_kernel<<<1, 64, 0, stream>>>(counts, offsets);
  bucket_kernel<<<T_TOK / 256, 256, 0, stream>>>(sel, selw, offsets, poscnt,
                                                 pair_token, pair_weight, pair_slot);
  cast_x_kernel<<<(T_TOK * H / 4) / 256, 256, 0, stream>>>(x, xb);
  transpose_cast_kernel<<<dim3(F / 64, H / 64, E), 256, 0, stream>>>(w1, w1t, H, F);
  transpose_cast_kernel<<<dim3(F / 64, H / 64, E), 256, 0, stream>>>(w3, w3t, H, F);
  transpose_cast_kernel<<<dim3(H / 64, F / 64, E), 256, 0, stream>>>(w2, w2t, F, H);
  gemm_h_kernel<<<dim3(E * TM2, F / 128), 512, 0, stream>>>(xb, w1t, w3t, pair_token,
                                                            counts, offsets, hbuf);
  gemm_out_kernel<<<dim3(E * TM2, H / 128), 256, 0, stream>>>(hbuf, w2t, pair_weight,
                                                              counts, offsets, po);
  combine_kernel<<<(T_TOK * H / 4) / 256, 256, 0, stream>>>(po, pair_slot, y);
}

// Round 5
// 538.829 us; speedup vs baseline: 2.5913x; 1.5090x over previous
//
#include <hip/hip_runtime.h>
#include <hip/hip_bf16.h>
#include <cstdint>

#define H 1024
#define F 2048
#define E 8
#define T_TOK 4096
#define NPAIR (T_TOK * 2)   // top-2 per token
#define BK 32               // K-step per LDS tile
#define TM2 32              // m-tiles of 128 per expert (4096/128)

typedef __attribute__((ext_vector_type(8))) short short8;
typedef __attribute__((ext_vector_type(4))) float f32x4;

__device__ __forceinline__ ushort f2bf(float f) {
  uint32_t u = __builtin_bit_cast(uint32_t, f);
  u += 0x7FFF + ((u >> 16) & 1);   // RNE
  return (ushort)(u >> 16);
}

// async global->LDS, 16B per lane; LDS dest = wave-uniform base + lane*16
__device__ __forceinline__ void async_copy16(const ushort* g, ushort* l) {
  __builtin_amdgcn_global_load_lds(
      (const __attribute__((address_space(1))) unsigned int*)g,
      (__attribute__((address_space(3))) unsigned int*)l, 16, 0, 0);
}

// ---------------- router: fp32 logits, softmax, top-2, counts ----------------
__global__ __launch_bounds__(256) void router_kernel(
    const float* __restrict__ x, const float* __restrict__ gw,
    float* __restrict__ logits_out, int* __restrict__ sel,
    float* __restrict__ selw, int* __restrict__ counts) {
  int tid = threadIdx.x;
  int t = blockIdx.x * 4 + (tid >> 6);   // one wave per token
  int l = tid & 63;
  const float4* xr = (const float4*)(x + (size_t)t * H);
  const float4* g4 = (const float4*)gw;
  float acc[E];
#pragma unroll
  for (int e = 0; e < E; ++e) acc[e] = 0.f;
#pragma unroll
  for (int i = 0; i < 4; ++i) {
    float4 xv = xr[l + 64 * i];
#pragma unroll
    for (int e = 0; e < E; ++e) {
      float4 gv = g4[e * (H / 4) + l + 64 * i];
      acc[e] += xv.x * gv.x + xv.y * gv.y + xv.z * gv.z + xv.w * gv.w;
    }
  }
#pragma unroll
  for (int off = 32; off > 0; off >>= 1)
#pragma unroll
    for (int e = 0; e < E; ++e) acc[e] += __shfl_xor(acc[e], off, 64);

  if (l == 0) {
    float m = acc[0];
    for (int e = 1; e < E; ++e) m = fmaxf(m, acc[e]);
    float p[E], den = 0.f;
    for (int e = 0; e < E; ++e) { p[e] = __expf(acc[e] - m); den += p[e]; }
    float inv = 1.f / den;
    int i0 = 0;
    for (int e = 1; e < E; ++e) if (acc[e] > acc[i0]) i0 = e;
    int i1 = (i0 == 0) ? 1 : 0;
    for (int e = 0; e < E; ++e) if (e != i0 && acc[e] > acc[i1]) i1 = e;
    for (int e = 0; e < E; ++e) logits_out[t * E + e] = acc[e];
    sel[t * 2] = i0; sel[t * 2 + 1] = i1;
    selw[t * 2] = p[i0] * inv; selw[t * 2 + 1] = p[i1] * inv;
    atomicAdd(&counts[i0], 1);
    atomicAdd(&counts[i1], 1);
  }
}

__global__ void offsets_kernel(const int* __restrict__ counts, int* __restrict__ offsets) {
  if (threadIdx.x == 0 && blockIdx.x == 0) {
    int s = 0;
    for (int e = 0; e < E; ++e) { offsets[e] = s; s += counts[e]; }
  }
}

__global__ __launch_bounds__(256) void bucket_kernel(
    const int* __restrict__ sel, const float* __restrict__ selw,
    const int* __restrict__ offsets, int* __restrict__ poscnt,
    int* __restrict__ pair_token, float* __restrict__ pair_weight,
    int* __restrict__ pair_slot) {
  int t = blockIdx.x * 256 + threadIdx.x;
  if (t >= T_TOK) return;
  for (int k = 0; k < 2; ++k) {
    int e = sel[t * 2 + k];
    int pos = atomicAdd(&poscnt[e], 1);
    int slot = offsets[e] + pos;
    pair_token[slot] = t;
    pair_weight[slot] = selw[t * 2 + k];
    pair_slot[t * 2 + k] = slot;
  }
}

// ---------------- dtype conversion ----------------
__global__ __launch_bounds__(256) void cast_x_kernel(const float* __restrict__ x,
                                                     ushort* __restrict__ xb) {
  int i = (blockIdx.x * 256 + threadIdx.x) * 4;
  float4 v = *(const float4*)(x + i);
  ushort4 o = make_ushort4(f2bf(v.x), f2bf(v.y), f2bf(v.z), f2bf(v.w));
  *(ushort4*)(xb + i) = o;
}

// src fp32 [e][R][C] -> dst bf16 [e][C][R]  (N-major so GEMM frags are K-contiguous)
__global__ __launch_bounds__(256) void transpose_cast_kernel(
    const float* __restrict__ src, ushort* __restrict__ dst, int R, int C) {
  __shared__ ushort tile[64][65];
  int e = blockIdx.z;
  src += (size_t)e * R * C;
  dst += (size_t)e * R * C;
  int r0 = blockIdx.y * 64, c0 = blockIdx.x * 64;
  int tid = threadIdx.x;
  int tr = tid >> 4, tc = (tid & 15) * 4;
#pragma unroll
  for (int i = 0; i < 4; ++i) {
    float4 v = *(const float4*)(src + (size_t)(r0 + tr + 16 * i) * C + c0 + tc);
    tile[tr + 16 * i][tc + 0] = f2bf(v.x);
    tile[tr + 16 * i][tc + 1] = f2bf(v.y);
    tile[tr + 16 * i][tc + 2] = f2bf(v.z);
    tile[tr + 16 * i][tc + 3] = f2bf(v.w);
  }
  __syncthreads();
#pragma unroll
  for (int i = 0; i < 4; ++i) {
    int dr = tr + 16 * i;           // dest row = source col
    ushort4 o;
    o.x = tile[tc + 0][dr]; o.y = tile[tc + 1][dr];
    o.z = tile[tc + 2][dr]; o.w = tile[tc + 3][dr];
    *(ushort4*)(dst + (size_t)(c0 + dr) * R + r0 + tc) = o;
  }
}

// ===================== GEMM tiles =====================
// LDS tile: 128 rows x BK(=32) k-elems, row-major, 64B/row (32 ushorts).
// Chunk swizzle: 16B slot s of row r holds k-chunk (s ^ ((r>>1)&3)).
// XCD affinity: blockIdx.x = expert; consecutive flat block ids round-robin
// over the 8 XCDs, so expert e's blocks land on XCD e -> A-set (~2MB) and
// current B f-tile (512KB) stay hot in that XCD's 4MB L2.

__device__ __forceinline__ int frag_off(int rr, int lkb) {   // ushort offset
  return rr * 32 + ((lkb ^ ((rr >> 1) & 3)) * 8);
}

// ---------------- grouped GEMM A: h = silu(x@w1) * (x@w3) ----------------
// 512 threads = 8 waves; wave tile 64x32 -> c1+c3 = 64 AGPR/wave.
__global__ __launch_bounds__(512) void gemm_h_kernel(
    const ushort* __restrict__ xb, const ushort* __restrict__ w1t,
    const ushort* __restrict__ w3t, const int* __restrict__ pair_token,
    const int* __restrict__ counts, const int* __restrict__ offsets,
    ushort* __restrict__ hbuf) {
  int e = blockIdx.x;                 // expert == XCD (affinity heuristic)
  int mt = blockIdx.y;
  int cnt = counts[e];
  int m0 = mt * 128;
  if (m0 >= cnt) return;
  int base = offsets[e];
  int f0 = blockIdx.z * 128;

  __shared__ ushort As[4096], B1s[4096], B3s[4096];   // 8 KB each

  int tid = threadIdx.x;
  int w = tid >> 6, l = tid & 63;     // w in 0..7
  int q = l >> 2, s = l & 3;

  // staging: wave w stages rows [w*16, w*16+16) of each of A, B1, B3
  int row = w * 16 + q;
  int g = s ^ ((row >> 1) & 3);       // swizzled global k-chunk

  int pA = base + m0 + row; if (pA >= base + cnt) pA = base + cnt - 1;
  const ushort* gA  = xb + (size_t)pair_token[pA] * H + g * 8;
  const ushort* gB1 = w1t + ((size_t)e * F + f0 + row) * H + g * 8;
  const ushort* gB3 = w3t + ((size_t)e * F + f0 + row) * H + g * 8;
  ushort* ldsA  = As  + w * 512;      // row (w*16) * 32 ushorts
  ushort* ldsB1 = B1s + w * 512;
  ushort* ldsB3 = B3s + w * 512;

  int wm = w >> 2, wn = w & 3;        // wave tile: rows wm*64+, cols wn*32+
  int lr = l & 15, lkb = l >> 4;

  int offA[4], offB[2];
#pragma unroll
  for (int ms = 0; ms < 4; ++ms) offA[ms] = frag_off(wm * 64 + ms * 16 + lr, lkb);
#pragma unroll
  for (int ns = 0; ns < 2; ++ns) offB[ns] = frag_off(wn * 32 + ns * 16 + lr, lkb);

  f32x4 c1[4][2], c3[4][2];
#pragma unroll
  for (int a = 0; a < 4; ++a)
#pragma unroll
    for (int b = 0; b < 2; ++b) { c1[a][b] = (f32x4)0.f; c3[a][b] = (f32x4)0.f; }

  for (int k0 = 0; k0 < H; k0 += BK) {
    __syncthreads();                    // prev-iter frag reads done
    async_copy16(gA, ldsA);
    async_copy16(gB1, ldsB1);
    async_copy16(gB3, ldsB3);
    gA += BK; gB1 += BK; gB3 += BK;
    __syncthreads();                    // drains vmcnt -> LDS valid

    short8 af[4], b1f[2], b3f[2];
#pragma unroll
    for (int ms = 0; ms < 4; ++ms) af[ms] = *(const short8*)(As + offA[ms]);
#pragma unroll
    for (int ns = 0; ns < 2; ++ns) {
      b1f[ns] = *(const short8*)(B1s + offB[ns]);
      b3f[ns] = *(const short8*)(B3s + offB[ns]);
    }
#pragma unroll
    for (int ms = 0; ms < 4; ++ms)
#pragma unroll
      for (int ns = 0; ns < 2; ++ns) {
        c1[ms][ns] = __builtin_amdgcn_mfma_f32_16x16x32_bf16(af[ms], b1f[ns], c1[ms][ns], 0, 0, 0);
        c3[ms][ns] = __builtin_amdgcn_mfma_f32_16x16x32_bf16(af[ms], b3f[ns], c3[ms][ns], 0, 0, 0);
      }
  }

#pragma unroll
  for (int ms = 0; ms < 4; ++ms)
#pragma unroll
    for (int ns = 0; ns < 2; ++ns)
#pragma unroll
      for (int rg = 0; rg < 4; ++rg) {
        int ml = wm * 64 + ms * 16 + (l >> 4) * 4 + rg;   // C/D: row=(lane>>4)*4+reg
        if (m0 + ml < cnt) {
          int nl = wn * 32 + ns * 16 + (l & 15);          // col=lane&15
          float gg = c1[ms][ns][rg], u = c3[ms][ns][rg];
          float hv = gg / (1.f + __expf(-gg)) * u;        // silu(g)*u
          hbuf[(size_t)(base + m0 + ml) * F + f0 + nl] = f2bf(hv);
        }
      }
}

// ---------------- grouped GEMM B: po = weight * (h @ w2), per-pair rows -------
// Same 8-wave structure + XCD affinity as gemm_h.
__global__ __launch_bounds__(512) void gemm_out_kernel(
    const ushort* __restrict__ hbuf, const ushort* __restrict__ w2t,
    const float* __restrict__ pair_weight, const int* __restrict__ counts,
    const int* __restrict__ offsets, float* __restrict__ po) {
  int e = blockIdx.x;                 // expert == XCD
  int mt = blockIdx.y;
  int cnt = counts[e];
  int m0 = mt * 128;
  if (m0 >= cnt) return;
  int base = offsets[e];
  int n0 = blockIdx.z * 128;

  __shared__ ushort As[4096], Bs[4096];
  __shared__ float wt_s[128];

  int tid = threadIdx.x;
  int w = tid >> 6, l = tid & 63;
  int q = l >> 2, s = l & 3;

  if (tid < 128) {
    int p = base + m0 + tid;
    if (p >= base + cnt) p = base + cnt - 1;
    wt_s[tid] = pair_weight[p];
  }

  int row = w * 16 + q;
  int g = s ^ ((row >> 1) & 3);

  int pA = base + m0 + row; if (pA >= base + cnt) pA = base + cnt - 1;
  const ushort* gA = hbuf + (size_t)pA * F + g * 8;
  const ushort* gB = w2t + ((size_t)e * H + n0 + row) * F + g * 8;
  ushort* ldsA = As + w * 512;
  ushort* ldsB = Bs + w * 512;

  int wm = w >> 2, wn = w & 3;
  int lr = l & 15, lkb = l >> 4;

  int offA[4], offB[2];
#pragma unroll
  for (int ms = 0; ms < 4; ++ms) offA[ms] = frag_off(wm * 64 + ms * 16 + lr, lkb);
#pragma unroll
  for (int ns = 0; ns < 2; ++ns) offB[ns] = frag_off(wn * 32 + ns * 16 + lr, lkb);

  f32x4 cc[4][2];
#pragma unroll
  for (int a = 0; a < 4; ++a)
#pragma unroll
    for (int b = 0; b < 2; ++b) cc[a][b] = (f32x4)0.f;

  for (int k0 = 0; k0 < F; k0 += BK) {
    __syncthreads();
    async_copy16(gA, ldsA);
    async_copy16(gB, ldsB);
    gA += BK; gB += BK;
    __syncthreads();

    short8 af[4], bf_[2];
#pragma unroll
    for (int ms = 0; ms < 4; ++ms) af[ms] = *(const short8*)(As + offA[ms]);
#pragma unroll
    for (int ns = 0; ns < 2; ++ns) bf_[ns] = *(const short8*)(Bs + offB[ns]);
#pragma unroll
    for (int ms = 0; ms < 4; ++ms)
#pragma unroll
      for (int ns = 0; ns < 2; ++ns)
        cc[ms][ns] = __builtin_amdgcn_mfma_f32_16x16x32_bf16(af[ms], bf_[ns], cc[ms][ns], 0, 0, 0);
  }

#pragma unroll
  for (int ms = 0; ms < 4; ++ms)
#pragma unroll
    for (int ns = 0; ns < 2; ++ns)
#pragma unroll
      for (int rg = 0; rg < 4; ++rg) {
        int ml = wm * 64 + ms * 16 + (l >> 4) * 4 + rg;
        if (m0 + ml < cnt) {
          int nl = wn * 32 + ns * 16 + (l & 15);
          po[(size_t)(base + m0 + ml) * H + n0 + nl] = cc[ms][ns][rg] * wt_s[ml];
        }
      }
}

// ---------------- combine: y[t] = po[slot0] + po[slot1] ----------------
__global__ __launch_bounds__(256) void combine_kernel(
    const float* __restrict__ po, const int* __restrict__ pair_slot,
    float* __restrict__ y) {
  int idx = blockIdx.x * 256 + threadIdx.x;    // over T*H/4
  int t = idx >> 8;                            // H/4 = 256 float4 per token
  int c = (idx & 255) * 4;
  int s0 = pair_slot[t * 2], s1 = pair_slot[t * 2 + 1];
  float4 a = *(const float4*)(po + (size_t)s0 * H + c);
  float4 b = *(const float4*)(po + (size_t)s1 * H + c);
  float4 o = make_float4(a.x + b.x, a.y + b.y, a.z + b.z, a.w + b.w);
  *(float4*)(y + (size_t)t * H + c) = o;
}

extern "C" void kernel_launch(void* const* d_in, const int* in_sizes, int n_in,
                              void* d_out, int out_size, void* d_ws, size_t ws_size,
                              hipStream_t stream) {
  const float* x  = (const float*)d_in[0];
  const float* gw = (const float*)d_in[1];
  const float* w1 = (const float*)d_in[2];
  const float* w3 = (const float*)d_in[3];
  const float* w2 = (const float*)d_in[4];
  float* y = (float*)d_out;                       // [T, H] fp32
  float* logits_out = y + (size_t)T_TOK * H;      // [T, E] fp32 (output #2)

  char* ws = (char*)d_ws;
  size_t off = 0;
  auto alloc = [&](size_t bytes) {
    char* p = ws + off;
    off += (bytes + 255) & ~size_t(255);
    return p;
  };
  ushort* xb   = (ushort*)alloc((size_t)T_TOK * H * 2);
  ushort* w1t  = (ushort*)alloc((size_t)E * F * H * 2);
  ushort* w3t  = (ushort*)alloc((size_t)E * F * H * 2);
  ushort* w2t  = (ushort*)alloc((size_t)E * H * F * 2);
  ushort* hbuf = (ushort*)alloc((size_t)(NPAIR + 128) * F * 2);
  int*   pair_token  = (int*)alloc(NPAIR * 4);
  float* pair_weight = (float*)alloc(NPAIR * 4);
  int*   pair_slot   = (int*)alloc(NPAIR * 4);
  int*   sel   = (int*)alloc(T_TOK * 2 * 4);
  float* selw  = (float*)alloc(T_TOK * 2 * 4);
  int* counts  = (int*)alloc(E * 4);
  int* offsets = (int*)alloc(E * 4);
  int* poscnt  = (int*)alloc(E * 4);
  // po aliases w1t: w1t (32 MB) is dead after gemm_h; po needs NPAIR*H*4 = 32 MB.
  float* po = (float*)w1t;

  hipMemsetAsync(counts, 0, E * 4, stream);
  hipMemsetAsync(poscnt, 0, E * 4, stream);

  router_kernel<<<T_TOK / 4, 256, 0, stream>>>(x, gw, logits_out, sel, selw, counts);
  offsets_kernel<<<1, 64, 0, stream>>>(counts, offsets);
  bucket_kernel<<<T_TOK / 256, 256, 0, stream>>>(sel, selw, offsets, poscnt,
                                                 pair_token, pair_weight, pair_slot);
  cast_x_kernel<<<(T_TOK * H / 4) / 256, 256, 0, stream>>>(x, xb);
  transpose_cast_kernel<<<dim3(F / 64, H / 64, E), 256, 0, stream>>>(w1, w1t, H, F);
  transpose_cast_kernel<<<dim3(F / 64, H / 64, E), 256, 0, stream>>>(w3, w3t, H, F);
  transpose_cast_kernel<<<dim3(H / 64, F / 64, E), 256, 0, stream>>>(w2, w2t, F, H);
  gemm_h_kernel<<<dim3(E, TM2, F / 128), 512, 0, stream>>>(xb, w1t, w3t, pair_token,
                                                           counts, offsets, hbuf);
  gemm_out_kernel<<<dim3(E, TM2, H / 128), 512, 0, stream>>>(hbuf, w2t, pair_weight,
                                                             counts, offsets, po);
  combine_kernel<<<(T_TOK * H / 4) / 256, 256, 0, stream>>>(po, pair_slot, y);
}